// Round 8
// baseline (269.770 us; speedup 1.0000x reference)
//
#include <hip/hip_runtime.h>

#define N_NODES 100000
#define N_EDGES 1600000
#define D 128
#define SCAN_CHUNK 1024
#define NB_SCAN ((N_NODES + SCAN_CHUNK - 1) / SCAN_CHUNK)  // 98

// bucket/partition config
#define BSHIFT 9
#define BUCK_NODES 512
#define NBUCK 196              // ceil(100000/512)
#define SCAP 12800             // padded arena records per bucket (mean ~11.5k)
#define PART_CHUNK 4096
#define PART_BLOCKS ((N_EDGES + PART_CHUNK - 1) / PART_CHUNK)  // 391
#define CONV_BLOCKS 6250
#define W_BLOCKS 128
#define PCUR_STRIDE 16         // one counter per 64B line

typedef __attribute__((ext_vector_type(8))) short bf16x8;
typedef __attribute__((ext_vector_type(4))) float f32x4;
typedef __attribute__((ext_vector_type(4))) unsigned u32x4;

__device__ __forceinline__ unsigned bf16rne(float f) {
  unsigned u = __float_as_uint(f);
  return (u + 0x7fffu + ((u >> 16) & 1u)) >> 16;
}

// ================= Tier-8 layout (int units) =================
// off    [200,100301)          CSR offsets (100001)
// fragW  [100304,116688)       swizzled bf16 B-fragments (32768 bf16)
// srt    [116688,3316688)      int2 {src,w} exact CSR order
// xh     [3316688,9718736)     x bf16 (100032 rows)
// stage  [9718736,14736336)    bucket arenas (196 x 12800 int2), 128B-aligned runs
// pcur   [14736336,+3136)      per-bucket PADDED cursors, 64B-strided
// pexact [14739472,+3136)      per-bucket EXACT counts, 64B-strided
#define T5_OFF    200
#define T5_FRAGW  100304
#define T5_SRT    116688
#define T5_XH     3316688
#define T8_STAGE  9718736
#define T8_PCUR   14736336
#define T8_PEXACT 14739472
#define WS_T5_BYTES ((size_t)16120784 * 4)

// ---- fallback layouts ----
#define WS_OFF   100000
#define WS_BSUM  200004
#define WS_SRT   200192
#define WS_XH    3400192
#define WS_T1_BYTES ((size_t)3400192 * 4)
#define WS_T2_BYTES ((size_t)(3400192 + 6400000) * 4)

// ============ k1: edge multi-split (LDS-staged, 128B-aligned block runs)
//              + x->bf16 + W swizzle ============
__global__ __launch_bounds__(256) void part_kernel(
    const int* __restrict__ ei, const float* __restrict__ ew,
    const float* __restrict__ x,
    const float* __restrict__ Wl, const float* __restrict__ Wa,
    int* __restrict__ pcur, int* __restrict__ pexact, int2* __restrict__ stage,
    uint4* __restrict__ xh4, unsigned short* __restrict__ fragW) {
  __shared__ int cntL[256];          // bucket hist (padded to 256)
  __shared__ int s0[256];            // inclusive prefix of cntL
  __shared__ int gb[NBUCK];          // PADDED global base per bucket (128B-aligned runs)
  __shared__ int curL[NBUCK];        // rank counters
  __shared__ int2 recL[PART_CHUNK];  // records ordered by bucket (32 KB)
  __shared__ unsigned char buckL[PART_CHUNK];  // bucket id per slot (4 KB)
  int bid = blockIdx.x, tid = threadIdx.x;

  if (bid < PART_BLOCKS) {
    cntL[tid] = 0;
    __syncthreads();
    int e0 = bid * PART_CHUNK;
    int tot = min(PART_CHUNK, N_EDGES - e0);
    // phase 1: histogram buckets
#pragma unroll
    for (int k = 0; k < PART_CHUNK / 256; k++) {
      int e = e0 + k * 256 + tid;
      if (e < N_EDGES) atomicAdd(&cntL[ei[e] >> BSHIFT], 1);
    }
    __syncthreads();
    // phase 2: inclusive scan over 256; padded (16-record) reservation
    s0[tid] = cntL[tid];
    __syncthreads();
    for (int o = 1; o < 256; o <<= 1) {
      int add = (tid >= o) ? s0[tid - o] : 0;
      __syncthreads();
      s0[tid] += add;
      __syncthreads();
    }
    if (tid < NBUCK) {
      int c = cntL[tid];
      int cp = (c + 15) & ~15;   // pad to 128 B: no line shared across blocks
      gb[tid] = atomicAdd(&pcur[tid * PCUR_STRIDE], cp);
      atomicAdd(&pexact[tid * PCUR_STRIDE], c);
      curL[tid] = 0;
    }
    __syncthreads();
    // phase 3: rank + place into LDS ordered by bucket (dense, valid only)
#pragma unroll
    for (int k = 0; k < PART_CHUNK / 256; k++) {
      int e = e0 + k * 256 + tid;
      if (e < N_EDGES) {
        int d = ei[e];
        int src = ei[N_EDGES + e];
        float w = ew[e];
        int b = d >> BSHIFT;
        int r = atomicAdd(&curL[b], 1);
        int slot = (s0[b] - cntL[b]) + r;
        recL[slot] = make_int2(src | ((d & (BUCK_NODES - 1)) << 17),
                               __float_as_int(w));
        buckL[slot] = (unsigned char)b;
      }
    }
    __syncthreads();
    // phase 4a: coalesced copy-out of valid records (contiguous from padded base)
    for (int i = tid; i < tot; i += 256) {
      int b = buckL[i];
      int idx = gb[b] + (i - (s0[b] - cntL[b]));
      stage[(size_t)b * SCAP + idx] = recL[i];
    }
    // phase 4b: sentinel-fill the pad tails (<=15 per bucket)
    for (int j = tid; j < NBUCK * 16; j += 256) {
      int b = j >> 4, k = j & 15;
      int c = cntL[b];
      int cp = (c + 15) & ~15;
      if (c + k < cp)
        stage[(size_t)b * SCAP + gb[b] + c + k] = make_int2(-1, 0);
    }
  } else if (bid < PART_BLOCKS + CONV_BLOCKS) {
    int g = (bid - PART_BLOCKS) * 256 + tid;  // [0, 1.6M) uint4 groups
    const u32x4* xp = reinterpret_cast<const u32x4*>(x);
    u32x4 a = __builtin_nontemporal_load(xp + (size_t)g * 2);
    u32x4 b = __builtin_nontemporal_load(xp + (size_t)g * 2 + 1);
    uint4 o;
    o.x = bf16rne(__uint_as_float(a.x)) | (bf16rne(__uint_as_float(a.y)) << 16);
    o.y = bf16rne(__uint_as_float(a.z)) | (bf16rne(__uint_as_float(a.w)) << 16);
    o.z = bf16rne(__uint_as_float(b.x)) | (bf16rne(__uint_as_float(b.y)) << 16);
    o.w = bf16rne(__uint_as_float(b.z)) | (bf16rne(__uint_as_float(b.w)) << 16);
    xh4[g] = o;
  } else {
    int tau = (bid - PART_BLOCKS - CONV_BLOCKS) * 256 + tid;  // 0..32767
    int slot = tau >> 3, j = tau & 7;
    int lane = slot & 63, ft = slot >> 6;
    int t = ft & 7, s = ft >> 3;
    int kl = (s & 3) * 32 + (lane >> 4) * 8 + j;
    int n = t * 16 + (lane & 15);
    float v = (s < 4 ? Wl : Wa)[kl * 128 + n];
    fragW[slot * 8 + j] = (unsigned short)bf16rne(v);
  }
}

// ============ k2: binB2 (1024 thr): parallel exact-count prefix + LDS hist
//              + scan + exact scatter (skips sentinels) ============
__global__ __launch_bounds__(1024) void binB2_kernel(const int* __restrict__ pcur,
                                                     const int* __restrict__ pexact,
                                                     const int2* __restrict__ stage,
                                                     int* __restrict__ off,
                                                     int2* __restrict__ srt) {
  __shared__ int pc[256];
  __shared__ int pcs[256];
  __shared__ int sa[BUCK_NODES];
  __shared__ int sb[BUCK_NODES];
  __shared__ int curL[BUCK_NODES];
  int b = blockIdx.x, tid = threadIdx.x;
  if (tid < 256) {
    int v = (tid < NBUCK) ? pexact[tid * PCUR_STRIDE] : 0;
    pc[tid] = v;
    pcs[tid] = v;
  }
  if (tid < BUCK_NODES) sa[tid] = 0;
  __syncthreads();
  // parallel inclusive scan over 256 exact bucket counts
  for (int o = 1; o < 256; o <<= 1) {
    int add = (tid < 256 && tid >= o) ? pcs[tid - o] : 0;
    __syncthreads();
    if (tid < 256) pcs[tid] += add;
    __syncthreads();
  }
  int base = pcs[b] - pc[b];          // exclusive scan of EXACT counts
  int m = pcur[b * PCUR_STRIDE];      // PADDED record count in arena
  const int2* sp = stage + (size_t)b * SCAP;
  for (int r = tid; r < m; r += 1024) {
    int rx = sp[r].x;
    if (rx != -1) atomicAdd(&sa[((unsigned)rx) >> 17], 1);
  }
  __syncthreads();
  // Hillis-Steele inclusive scan over 512 node counts (dbl-buf)
  int* srcb = sa;
  int* dstb = sb;
  for (int o = 1; o < BUCK_NODES; o <<= 1) {
    if (tid < BUCK_NODES)
      dstb[tid] = srcb[tid] + (tid >= o ? srcb[tid - o] : 0);
    __syncthreads();
    int* t = srcb; srcb = dstb; dstb = t;
  }
  int nb = b << BSHIFT;
  int nn = min(BUCK_NODES, N_NODES - nb);
  if (tid < BUCK_NODES) {
    int ex = tid ? srcb[tid - 1] : 0;
    curL[tid] = ex;
    if (tid < nn) off[nb + tid] = base + ex;
  }
  if (tid == 0 && b == 0) off[N_NODES] = N_EDGES;
  __syncthreads();
  for (int r = tid; r < m; r += 1024) {
    int2 rec = sp[r];
    if (rec.x != -1) {
      int ldst = ((unsigned)rec.x) >> 17;
      int s = atomicAdd(&curL[ldst], 1);
      srt[base + s] = make_int2(rec.x & 0x1FFFF, rec.y);
    }
  }
}

// ============ k3: FUSED gather+GEMM (unchanged from r4) ============
#define FACC(s_, p_, w_)                                                    \
  {                                                                         \
    acc1[s_][0] = fmaf(w_, __uint_as_float((p_).x << 16), acc1[s_][0]);     \
    acc1[s_][1] = fmaf(w_, __uint_as_float((p_).x & 0xffff0000u), acc1[s_][1]); \
    acc1[s_][2] = fmaf(w_, __uint_as_float((p_).y << 16), acc1[s_][2]);     \
    acc1[s_][3] = fmaf(w_, __uint_as_float((p_).y & 0xffff0000u), acc1[s_][3]); \
    acc1[s_][4] = fmaf(w_, __uint_as_float((p_).z << 16), acc1[s_][4]);     \
    acc1[s_][5] = fmaf(w_, __uint_as_float((p_).z & 0xffff0000u), acc1[s_][5]); \
    acc1[s_][6] = fmaf(w_, __uint_as_float((p_).w << 16), acc1[s_][6]);     \
    acc1[s_][7] = fmaf(w_, __uint_as_float((p_).w & 0xffff0000u), acc1[s_][7]); \
  }

__global__ __launch_bounds__(256) void fused_gather_gemm_kernel(
    const uint4* __restrict__ xh4, const short* __restrict__ xh,
    const short* __restrict__ fragW, const int* __restrict__ off,
    const int2* __restrict__ srt,
    const float* __restrict__ bl, const float* __restrict__ ba,
    float* __restrict__ out) {
  int tid = threadIdx.x;
  int wave = tid >> 6, lane = tid & 63;
  int m = lane & 15, q = lane >> 4;
  int R = blockIdx.x * 64 + wave * 16;
  int n = R + m;

  // ---- phase 1: gather z fragment into registers ----
  float acc1[4][8];
#pragma unroll
  for (int s = 0; s < 4; s++)
#pragma unroll
    for (int j = 0; j < 8; j++) acc1[s][j] = 0.f;

  int beg = 0, end = 0;
  if (n < N_NODES) {
    beg = off[n];
    end = off[n + 1];
  }
  int e = beg;
  for (; e + 1 < end; e += 2) {
    int2 r0 = srt[e];
    int2 r1 = srt[e + 1];
    uint4 p00 = xh4[(size_t)r0.x * 16 + 0 * 4 + q];
    uint4 p01 = xh4[(size_t)r0.x * 16 + 1 * 4 + q];
    uint4 p02 = xh4[(size_t)r0.x * 16 + 2 * 4 + q];
    uint4 p03 = xh4[(size_t)r0.x * 16 + 3 * 4 + q];
    uint4 p10 = xh4[(size_t)r1.x * 16 + 0 * 4 + q];
    uint4 p11 = xh4[(size_t)r1.x * 16 + 1 * 4 + q];
    uint4 p12 = xh4[(size_t)r1.x * 16 + 2 * 4 + q];
    uint4 p13 = xh4[(size_t)r1.x * 16 + 3 * 4 + q];
    float w0 = __int_as_float(r0.y), w1 = __int_as_float(r1.y);
    FACC(0, p00, w0) FACC(1, p01, w0) FACC(2, p02, w0) FACC(3, p03, w0)
    FACC(0, p10, w1) FACC(1, p11, w1) FACC(2, p12, w1) FACC(3, p13, w1)
  }
  if (e < end) {
    int2 r0 = srt[e];
    uint4 p00 = xh4[(size_t)r0.x * 16 + 0 * 4 + q];
    uint4 p01 = xh4[(size_t)r0.x * 16 + 1 * 4 + q];
    uint4 p02 = xh4[(size_t)r0.x * 16 + 2 * 4 + q];
    uint4 p03 = xh4[(size_t)r0.x * 16 + 3 * 4 + q];
    float w0 = __int_as_float(r0.y);
    FACC(0, p00, w0) FACC(1, p01, w0) FACC(2, p02, w0) FACC(3, p03, w0)
  }

  // pack to bf16 A-fragments
  bf16x8 az[4];
#pragma unroll
  for (int s = 0; s < 4; s++) {
    union { bf16x8 v; unsigned u[4]; } cv;
#pragma unroll
    for (int jj = 0; jj < 4; jj++)
      cv.u[jj] = bf16rne(acc1[s][2 * jj]) | (bf16rne(acc1[s][2 * jj + 1]) << 16);
    az[s] = cv.v;
  }

  // ---- phase 2: MFMA out = [xh | z] @ [Wl; Wa] + bl + deg*ba ----
  const short* xrow = xh + (size_t)n * D + q * 8;
  const short* fw = fragW + (size_t)lane * 8;
  f32x4 acc[8];
#pragma unroll
  for (int t = 0; t < 8; t++) acc[t] = (f32x4){0.f, 0.f, 0.f, 0.f};

#pragma unroll
  for (int s = 0; s < 8; s++) {
    bf16x8 a;
    if (s < 4)
      a = *reinterpret_cast<const bf16x8*>(xrow + s * 32);
    else
      a = az[s - 4];
#pragma unroll
    for (int t = 0; t < 8; t++) {
      bf16x8 b = *reinterpret_cast<const bf16x8*>(fw + (size_t)((s * 8 + t) * 64) * 8);
      acc[t] = __builtin_amdgcn_mfma_f32_16x16x32_bf16(a, b, acc[t], 0, 0, 0);
    }
  }

  float blv[8], bav[8];
#pragma unroll
  for (int t = 0; t < 8; t++) {
    blv[t] = bl[t * 16 + m];
    bav[t] = ba[t * 16 + m];
  }
#pragma unroll
  for (int r = 0; r < 4; r++) {
    int row = R + q * 4 + r;
    if (row < N_NODES) {
      float dg = (float)(off[row + 1] - off[row]);
#pragma unroll
      for (int t = 0; t < 8; t++)
        __builtin_nontemporal_store(acc[t][r] + blv[t] + dg * bav[t],
                                    out + (size_t)row * D + t * 16 + m);
    }
  }
}

// ================= fallback kernels (tiers 0-2) =================

__global__ __launch_bounds__(256) void hist_kernel(const int* __restrict__ ei,
                                                   int* __restrict__ cnt) {
  int e = blockIdx.x * 256 + threadIdx.x;
  if (e < N_EDGES) atomicAdd(&cnt[ei[e]], 1);
}

__global__ __launch_bounds__(256) void block_sum_kernel(const int* __restrict__ cnt,
                                                        int* __restrict__ bsum) {
  int base = blockIdx.x * SCAN_CHUNK;
  int s = 0;
#pragma unroll
  for (int k = 0; k < 4; k++) {
    int i = base + (int)threadIdx.x + k * 256;
    if (i < N_NODES) s += cnt[i];
  }
  __shared__ int red[4];
  for (int o = 32; o > 0; o >>= 1) s += __shfl_down(s, o, 64);
  if ((threadIdx.x & 63) == 0) red[threadIdx.x >> 6] = s;
  __syncthreads();
  if (threadIdx.x == 0) bsum[blockIdx.x] = red[0] + red[1] + red[2] + red[3];
}

__global__ __launch_bounds__(128) void scan_bsum_kernel(int* __restrict__ bsum,
                                                        int* __restrict__ off) {
  __shared__ int sh[128];
  int t = threadIdx.x;
  int v = (t < NB_SCAN) ? bsum[t] : 0;
  sh[t] = v;
  __syncthreads();
  for (int o = 1; o < 128; o <<= 1) {
    int add = (t >= o) ? sh[t - o] : 0;
    __syncthreads();
    sh[t] += add;
    __syncthreads();
  }
  if (t < NB_SCAN) bsum[t] = sh[t] - v;
  if (t == 0) off[N_NODES] = sh[127];
}

__global__ __launch_bounds__(256) void scan_offsets_kernel(const int* __restrict__ cnt,
                                                           const int* __restrict__ bsum,
                                                           int* __restrict__ off) {
  __shared__ int sh[256];
  int t = threadIdx.x;
  int i0 = blockIdx.x * SCAN_CHUNK + t * 4;
  int c[4];
#pragma unroll
  for (int k = 0; k < 4; k++) c[k] = (i0 + k < N_NODES) ? cnt[i0 + k] : 0;
  int ls = c[0] + c[1] + c[2] + c[3];
  sh[t] = ls;
  __syncthreads();
  for (int o = 1; o < 256; o <<= 1) {
    int add = (t >= o) ? sh[t - o] : 0;
    __syncthreads();
    sh[t] += add;
    __syncthreads();
  }
  int run = bsum[blockIdx.x] + sh[t] - ls;
#pragma unroll
  for (int k = 0; k < 4; k++) {
    if (i0 + k < N_NODES) off[i0 + k] = run;
    run += c[k];
  }
}

__global__ __launch_bounds__(256) void fill_kernel(const int* __restrict__ ei,
                                                   const float* __restrict__ ew,
                                                   const int* __restrict__ off,
                                                   int* __restrict__ cur,
                                                   int2* __restrict__ srt) {
  int e = blockIdx.x * 256 + threadIdx.x;
  if (e >= N_EDGES) return;
  int dst = ei[e];
  int p = off[dst] + atomicAdd(&cur[dst], 1);
  srt[p] = make_int2(ei[N_EDGES + e], __float_as_int(ew[e]));
}

__global__ __launch_bounds__(256) void convert_kernel(const float* __restrict__ x,
                                                      uint4* __restrict__ xh) {
  int i = blockIdx.x * 256 + threadIdx.x;
  const float4* xp = reinterpret_cast<const float4*>(x);
  float4 a = xp[(size_t)i * 2];
  float4 b = xp[(size_t)i * 2 + 1];
  uint4 o;
  o.x = bf16rne(a.x) | (bf16rne(a.y) << 16);
  o.y = bf16rne(a.z) | (bf16rne(a.w) << 16);
  o.z = bf16rne(b.x) | (bf16rne(b.y) << 16);
  o.w = bf16rne(b.z) | (bf16rne(b.w) << 16);
  xh[i] = o;
}

__global__ __launch_bounds__(256) void gather_bf16_kernel(const unsigned* __restrict__ xh,
                                                          const int* __restrict__ off,
                                                          const int2* __restrict__ srt,
                                                          float* __restrict__ z,
                                                          float* __restrict__ degf) {
  int gid = blockIdx.x * 256 + threadIdx.x;
  int n = gid >> 5;
  int lane = gid & 31;
  if (n >= N_NODES) return;
  int beg = off[n], end = off[n + 1];
  float4 acc = make_float4(0.f, 0.f, 0.f, 0.f);
  int e = beg;
  for (; e + 1 < end; e += 2) {
    int2 r0 = srt[e];
    int2 r1 = srt[e + 1];
    uint2 p0 = *reinterpret_cast<const uint2*>(xh + (size_t)r0.x * 64 + lane * 2);
    uint2 p1 = *reinterpret_cast<const uint2*>(xh + (size_t)r1.x * 64 + lane * 2);
    float w0 = __int_as_float(r0.y);
    float w1 = __int_as_float(r1.y);
    acc.x = fmaf(w0, __uint_as_float(p0.x << 16), acc.x);
    acc.y = fmaf(w0, __uint_as_float(p0.x & 0xffff0000u), acc.y);
    acc.z = fmaf(w0, __uint_as_float(p0.y << 16), acc.z);
    acc.w = fmaf(w0, __uint_as_float(p0.y & 0xffff0000u), acc.w);
    acc.x = fmaf(w1, __uint_as_float(p1.x << 16), acc.x);
    acc.y = fmaf(w1, __uint_as_float(p1.x & 0xffff0000u), acc.y);
    acc.z = fmaf(w1, __uint_as_float(p1.y << 16), acc.z);
    acc.w = fmaf(w1, __uint_as_float(p1.y & 0xffff0000u), acc.w);
  }
  if (e < end) {
    int2 r0 = srt[e];
    uint2 p0 = *reinterpret_cast<const uint2*>(xh + (size_t)r0.x * 64 + lane * 2);
    float w0 = __int_as_float(r0.y);
    acc.x = fmaf(w0, __uint_as_float(p0.x << 16), acc.x);
    acc.y = fmaf(w0, __uint_as_float(p0.x & 0xffff0000u), acc.y);
    acc.z = fmaf(w0, __uint_as_float(p0.y << 16), acc.z);
    acc.w = fmaf(w0, __uint_as_float(p0.y & 0xffff0000u), acc.w);
  }
  *reinterpret_cast<float4*>(z + (size_t)n * D + (lane << 2)) = acc;
  if (lane == 0) degf[n] = (float)(end - beg);
}

__global__ __launch_bounds__(256) void gather_f32_kernel(const float* __restrict__ x,
                                                         const int* __restrict__ off,
                                                         const int2* __restrict__ srt,
                                                         float* __restrict__ z,
                                                         float* __restrict__ degf) {
  int gid = blockIdx.x * 256 + threadIdx.x;
  int n = gid >> 5;
  int lane = gid & 31;
  if (n >= N_NODES) return;
  int beg = off[n], end = off[n + 1];
  float4 acc = make_float4(0.f, 0.f, 0.f, 0.f);
  for (int e = beg; e < end; e++) {
    int2 r0 = srt[e];
    float4 x0 = *reinterpret_cast<const float4*>(x + (size_t)r0.x * D + (lane << 2));
    float w0 = __int_as_float(r0.y);
    acc.x = fmaf(w0, x0.x, acc.x); acc.y = fmaf(w0, x0.y, acc.y);
    acc.z = fmaf(w0, x0.z, acc.z); acc.w = fmaf(w0, x0.w, acc.w);
  }
  *reinterpret_cast<float4*>(z + (size_t)n * D + (lane << 2)) = acc;
  if (lane == 0) degf[n] = (float)(end - beg);
}

__global__ __launch_bounds__(256) void scatter_kernel(const float* __restrict__ x,
                                                      const int* __restrict__ ei,
                                                      const float* __restrict__ ew,
                                                      float* __restrict__ z,
                                                      float* __restrict__ deg) {
  long long g = (long long)blockIdx.x * 256 + threadIdx.x;
  int e = (int)(g >> 5);
  int lane = (int)(g & 31);
  if (e >= N_EDGES) return;
  int dst = ei[e];
  int src = ei[N_EDGES + e];
  float w = ew[e];
  float4 xv = *reinterpret_cast<const float4*>(x + (size_t)src * D + (lane << 2));
  float* o = z + (size_t)dst * D + (lane << 2);
  atomicAdd(o + 0, w * xv.x);
  atomicAdd(o + 1, w * xv.y);
  atomicAdd(o + 2, w * xv.z);
  atomicAdd(o + 3, w * xv.w);
  if (lane == 0) atomicAdd(deg + dst, 1.0f);
}

__global__ __launch_bounds__(256) void fused_gemm_kernel(const float* __restrict__ x,
                                                         const float* __restrict__ Wl,
                                                         const float* __restrict__ bl,
                                                         const float* __restrict__ Wa,
                                                         const float* __restrict__ ba,
                                                         const float* __restrict__ deg,
                                                         float* __restrict__ out) {
  __shared__ float xs[32 * 16];
  __shared__ float zs[32 * 16];
  __shared__ float wls[16 * 128];
  __shared__ float was[16 * 128];
  const int tid = threadIdx.x;
  const int row0 = blockIdx.x * 32;
  const int c4 = tid & 31;
  const int r0 = tid >> 5;
  float4 acc[4];
#pragma unroll
  for (int i = 0; i < 4; i++) acc[i] = make_float4(0.f, 0.f, 0.f, 0.f);

  for (int k0 = 0; k0 < D; k0 += 16) {
    {
      int t = tid & 127;
      int r = t >> 2;
      int kc = (t & 3) << 2;
      const float* sp = (tid < 128) ? x : out;
      float* dp = (tid < 128) ? xs : zs;
      *reinterpret_cast<float4*>(dp + r * 16 + kc) =
          *reinterpret_cast<const float4*>(sp + (size_t)(row0 + r) * D + k0 + kc);
    }
#pragma unroll
    for (int i = 0; i < 2; i++) {
      int f = tid + i * 256;
      int kk = f >> 5;
      int cc = (f & 31) << 2;
      *reinterpret_cast<float4*>(wls + kk * 128 + cc) =
          *reinterpret_cast<const float4*>(Wl + (size_t)(k0 + kk) * D + cc);
      *reinterpret_cast<float4*>(was + kk * 128 + cc) =
          *reinterpret_cast<const float4*>(Wa + (size_t)(k0 + kk) * D + cc);
    }
    __syncthreads();
#pragma unroll
    for (int kk = 0; kk < 16; kk++) {
      float4 wl = *reinterpret_cast<const float4*>(wls + kk * 128 + (c4 << 2));
      float4 wa = *reinterpret_cast<const float4*>(was + kk * 128 + (c4 << 2));
#pragma unroll
      for (int rr = 0; rr < 4; rr++) {
        int r2 = r0 + rr * 8;
        float xv = xs[r2 * 16 + kk];
        float zv = zs[r2 * 16 + kk];
        acc[rr].x = fmaf(xv, wl.x, fmaf(zv, wa.x, acc[rr].x));
        acc[rr].y = fmaf(xv, wl.y, fmaf(zv, wa.y, acc[rr].y));
        acc[rr].z = fmaf(xv, wl.z, fmaf(zv, wa.z, acc[rr].z));
        acc[rr].w = fmaf(xv, wl.w, fmaf(zv, wa.w, acc[rr].w));
      }
    }
    __syncthreads();
  }

  float4 blv = *reinterpret_cast<const float4*>(bl + (c4 << 2));
  float4 bav = *reinterpret_cast<const float4*>(ba + (c4 << 2));
#pragma unroll
  for (int rr = 0; rr < 4; rr++) {
    int r = row0 + r0 + rr * 8;
    float d = deg[r];
    float4 o;
    o.x = acc[rr].x + blv.x + d * bav.x;
    o.y = acc[rr].y + blv.y + d * bav.y;
    o.z = acc[rr].z + blv.z + d * bav.z;
    o.w = acc[rr].w + blv.w + d * bav.w;
    *reinterpret_cast<float4*>(out + (size_t)r * D + (c4 << 2)) = o;
  }
}

extern "C" void kernel_launch(void* const* d_in, const int* in_sizes, int n_in,
                              void* d_out, int out_size, void* d_ws, size_t ws_size,
                              hipStream_t stream) {
  const float* x  = (const float*)d_in[0];
  const int*   ei = (const int*)d_in[1];
  const float* ew = (const float*)d_in[2];
  const float* Wl = (const float*)d_in[3];
  const float* bl = (const float*)d_in[4];
  const float* Wa = (const float*)d_in[5];
  const float* ba = (const float*)d_in[6];
  float* out = (float*)d_out;

  if (ws_size >= WS_T5_BYTES) {
    int* ws = (int*)d_ws;
    int* off = ws + T5_OFF;
    unsigned short* fragW = (unsigned short*)(ws + T5_FRAGW);
    int2* srt = (int2*)(ws + T5_SRT);
    unsigned* xh = (unsigned*)(ws + T5_XH);
    int2* stage = (int2*)(ws + T8_STAGE);
    int* pcur = ws + T8_PCUR;
    int* pexact = ws + T8_PEXACT;

    // zero pcur + pexact (contiguous)
    hipMemsetAsync(pcur, 0, 2 * NBUCK * PCUR_STRIDE * sizeof(int), stream);
    part_kernel<<<PART_BLOCKS + CONV_BLOCKS + W_BLOCKS, 256, 0, stream>>>(
        ei, ew, x, Wl, Wa, pcur, pexact, stage, (uint4*)xh, fragW);
    binB2_kernel<<<NBUCK, 1024, 0, stream>>>(pcur, pexact, stage, off, srt);
    fused_gather_gemm_kernel<<<1563, 256, 0, stream>>>(
        (const uint4*)xh, (const short*)xh, (const short*)fragW, off, srt,
        bl, ba, out);
  } else if (ws_size >= WS_T1_BYTES) {
    int*  cnt  = (int*)d_ws;
    int*  off  = cnt + WS_OFF;
    int*  bsum = cnt + WS_BSUM;
    int2* srt  = (int2*)(cnt + WS_SRT);
    float* degf = (float*)cnt;

    hipMemsetAsync(cnt, 0, (size_t)N_NODES * sizeof(int), stream);
    hist_kernel<<<(N_EDGES + 255) / 256, 256, 0, stream>>>(ei, cnt);
    block_sum_kernel<<<NB_SCAN, 256, 0, stream>>>(cnt, bsum);
    scan_bsum_kernel<<<1, 128, 0, stream>>>(bsum, off);
    scan_offsets_kernel<<<NB_SCAN, 256, 0, stream>>>(cnt, bsum, off);
    hipMemsetAsync(cnt, 0, (size_t)N_NODES * sizeof(int), stream);
    fill_kernel<<<(N_EDGES + 255) / 256, 256, 0, stream>>>(ei, ew, off, cnt, srt);

    if (ws_size >= WS_T2_BYTES) {
      unsigned* xh = (unsigned*)(cnt + WS_XH);
      convert_kernel<<<(N_NODES * D / 8) / 256, 256, 0, stream>>>(x, (uint4*)xh);
      gather_bf16_kernel<<<(N_NODES * 32 + 255) / 256, 256, 0, stream>>>(xh, off, srt, out, degf);
    } else {
      gather_f32_kernel<<<(N_NODES * 32 + 255) / 256, 256, 0, stream>>>(x, off, srt, out, degf);
    }
    fused_gemm_kernel<<<N_NODES / 32, 256, 0, stream>>>(x, Wl, bl, Wa, ba, degf, out);
  } else {
    float* deg = (float*)d_ws;
    hipMemsetAsync(out, 0, (size_t)N_NODES * D * sizeof(float), stream);
    hipMemsetAsync(deg, 0, (size_t)N_NODES * sizeof(float), stream);
    scatter_kernel<<<(N_EDGES * 32) / 256, 256, 0, stream>>>(x, ei, ew, out, deg);
    fused_gemm_kernel<<<N_NODES / 32, 256, 0, stream>>>(x, Wl, bl, Wa, ba, deg, out);
  }
}

// Round 9
// 261.847 us; speedup vs baseline: 1.0303x; 1.0303x over previous
//
#include <hip/hip_runtime.h>

#define N_NODES 100000
#define N_EDGES 1600000
#define D 128
#define SCAN_CHUNK 1024
#define NB_SCAN ((N_NODES + SCAN_CHUNK - 1) / SCAN_CHUNK)  // 98

// bucket/partition config
#define BSHIFT 9
#define BUCK_NODES 512
#define NBUCK 196              // ceil(100000/512)
#define SCAP 10240             // stage arena records per bucket (mean 8163)
#define PART_CHUNK 4096
#define PART_BLOCKS ((N_EDGES + PART_CHUNK - 1) / PART_CHUNK)  // 391
#define CONV_BLOCKS 6250
#define W_BLOCKS 128
#define PCUR_STRIDE 16         // one counter per 64B line

typedef __attribute__((ext_vector_type(8))) short bf16x8;
typedef __attribute__((ext_vector_type(4))) float f32x4;
typedef __attribute__((ext_vector_type(4))) unsigned u32x4;

__device__ __forceinline__ unsigned bf16rne(float f) {
  unsigned u = __float_as_uint(f);
  return (u + 0x7fffu + ((u >> 16) & 1u)) >> 16;
}

// ================= Tier-7 layout (int units) =================
// off   [200,100301)         CSR offsets (100001)
// fragW [100304,116688)      swizzled bf16 B-fragments (32768 bf16)
// srt   [116688,3316688)     int2 {src,w} exact CSR order
// xh    [3316688,9718736)    x bf16 (100032 rows)
// stage [9718736,13732816)   bucket arenas (196 x 10240 int2)
// pcur  [13732816,+3136)     per-bucket cursors, 64B-strided
#define T5_OFF    200
#define T5_FRAGW  100304
#define T5_SRT    116688
#define T5_XH     3316688
#define T5_ZH     9718736
#define T7_PCUR   13732816
#define WS_T5_BYTES ((size_t)16120784 * 4)

// ---- fallback layouts ----
#define WS_OFF   100000
#define WS_BSUM  200004
#define WS_SRT   200192
#define WS_XH    3400192
#define WS_T1_BYTES ((size_t)3400192 * 4)
#define WS_T2_BYTES ((size_t)(3400192 + 6400000) * 4)

// ============ k1: edge multi-split (LDS-staged coalesced stores)
//              + x->bf16 + W swizzle ============
__global__ __launch_bounds__(256) void part_kernel(
    const int* __restrict__ ei, const float* __restrict__ ew,
    const float* __restrict__ x,
    const float* __restrict__ Wl, const float* __restrict__ Wa,
    int* __restrict__ pcur, int2* __restrict__ stage,
    uint4* __restrict__ xh4, unsigned short* __restrict__ fragW) {
  __shared__ int cntL[256];          // bucket hist (padded to 256)
  __shared__ int s0[256];            // inclusive prefix of cntL
  __shared__ int gb[NBUCK];          // global reservation base per bucket
  __shared__ int curL[NBUCK];        // rank counters
  __shared__ int2 recL[PART_CHUNK];  // records ordered by bucket (32 KB)
  __shared__ unsigned char buckL[PART_CHUNK];  // bucket id per slot (4 KB)
  int bid = blockIdx.x, tid = threadIdx.x;

  if (bid < PART_BLOCKS) {
    cntL[tid] = 0;
    __syncthreads();
    int e0 = bid * PART_CHUNK;
    int tot = min(PART_CHUNK, N_EDGES - e0);
    // phase 1: histogram buckets
#pragma unroll
    for (int k = 0; k < PART_CHUNK / 256; k++) {
      int e = e0 + k * 256 + tid;
      if (e < N_EDGES) atomicAdd(&cntL[ei[e] >> BSHIFT], 1);
    }
    __syncthreads();
    // phase 2: inclusive scan over 256
    s0[tid] = cntL[tid];
    __syncthreads();
    for (int o = 1; o < 256; o <<= 1) {
      int add = (tid >= o) ? s0[tid - o] : 0;
      __syncthreads();
      s0[tid] += add;
      __syncthreads();
    }
    if (tid < NBUCK) {
      gb[tid] = atomicAdd(&pcur[tid * PCUR_STRIDE], cntL[tid]);
      curL[tid] = 0;
    }
    __syncthreads();
    // phase 3: rank + place into LDS ordered by bucket
#pragma unroll
    for (int k = 0; k < PART_CHUNK / 256; k++) {
      int e = e0 + k * 256 + tid;
      if (e < N_EDGES) {
        int d = ei[e];
        int src = ei[N_EDGES + e];
        float w = ew[e];
        int b = d >> BSHIFT;
        int r = atomicAdd(&curL[b], 1);
        int slot = (s0[b] - cntL[b]) + r;
        recL[slot] = make_int2(src | ((d & (BUCK_NODES - 1)) << 17),
                               __float_as_int(w));
        buckL[slot] = (unsigned char)b;
      }
    }
    __syncthreads();
    // phase 4: coalesced copy-out (consecutive slots -> consecutive addrs)
    for (int i = tid; i < tot; i += 256) {
      int b = buckL[i];
      int idx = gb[b] + (i - (s0[b] - cntL[b]));
      stage[(size_t)b * SCAP + idx] = recL[i];
    }
  } else if (bid < PART_BLOCKS + CONV_BLOCKS) {
    int g = (bid - PART_BLOCKS) * 256 + tid;  // [0, 1.6M) uint4 groups
    const u32x4* xp = reinterpret_cast<const u32x4*>(x);
    u32x4 a = __builtin_nontemporal_load(xp + (size_t)g * 2);
    u32x4 b = __builtin_nontemporal_load(xp + (size_t)g * 2 + 1);
    uint4 o;
    o.x = bf16rne(__uint_as_float(a.x)) | (bf16rne(__uint_as_float(a.y)) << 16);
    o.y = bf16rne(__uint_as_float(a.z)) | (bf16rne(__uint_as_float(a.w)) << 16);
    o.z = bf16rne(__uint_as_float(b.x)) | (bf16rne(__uint_as_float(b.y)) << 16);
    o.w = bf16rne(__uint_as_float(b.z)) | (bf16rne(__uint_as_float(b.w)) << 16);
    xh4[g] = o;
  } else {
    int tau = (bid - PART_BLOCKS - CONV_BLOCKS) * 256 + tid;  // 0..32767
    int slot = tau >> 3, j = tau & 7;
    int lane = slot & 63, ft = slot >> 6;
    int t = ft & 7, s = ft >> 3;
    int kl = (s & 3) * 32 + (lane >> 4) * 8 + j;
    int n = t * 16 + (lane & 15);
    float v = (s < 4 ? Wl : Wa)[kl * 128 + n];
    fragW[slot * 8 + j] = (unsigned short)bf16rne(v);
  }
}

// ============ k2: binB2 (1024 thr): parallel bucket-prefix + LDS hist
//              + scan + exact scatter ============
__global__ __launch_bounds__(1024) void binB2_kernel(const int* __restrict__ pcur,
                                                     const int2* __restrict__ stage,
                                                     int* __restrict__ off,
                                                     int2* __restrict__ srt) {
  __shared__ int pc[256];
  __shared__ int pcs[256];
  __shared__ int sa[BUCK_NODES];
  __shared__ int sb[BUCK_NODES];
  __shared__ int curL[BUCK_NODES];
  int b = blockIdx.x, tid = threadIdx.x;
  if (tid < 256) {
    int v = (tid < NBUCK) ? pcur[tid * PCUR_STRIDE] : 0;
    pc[tid] = v;
    pcs[tid] = v;
  }
  if (tid < BUCK_NODES) sa[tid] = 0;
  __syncthreads();
  // parallel inclusive scan over 256 bucket counts (replaces serial-196 loop)
  for (int o = 1; o < 256; o <<= 1) {
    int add = (tid < 256 && tid >= o) ? pcs[tid - o] : 0;
    __syncthreads();
    if (tid < 256) pcs[tid] += add;
    __syncthreads();
  }
  int base = pcs[b] - pc[b];
  int m = pc[b];
  const int2* sp = stage + (size_t)b * SCAP;
  for (int r = tid; r < m; r += 1024)
    atomicAdd(&sa[((unsigned)sp[r].x) >> 17], 1);
  __syncthreads();
  // Hillis-Steele inclusive scan over 512 node counts (dbl-buf)
  int* srcb = sa;
  int* dstb = sb;
  for (int o = 1; o < BUCK_NODES; o <<= 1) {
    if (tid < BUCK_NODES)
      dstb[tid] = srcb[tid] + (tid >= o ? srcb[tid - o] : 0);
    __syncthreads();
    int* t = srcb; srcb = dstb; dstb = t;
  }
  int nb = b << BSHIFT;
  int nn = min(BUCK_NODES, N_NODES - nb);
  if (tid < BUCK_NODES) {
    int ex = tid ? srcb[tid - 1] : 0;
    curL[tid] = ex;
    if (tid < nn) off[nb + tid] = base + ex;
  }
  if (tid == 0 && b == 0) off[N_NODES] = N_EDGES;  // total is exactly N_EDGES
  __syncthreads();
  for (int r = tid; r < m; r += 1024) {
    int2 rec = sp[r];
    int ldst = ((unsigned)rec.x) >> 17;
    int s = atomicAdd(&curL[ldst], 1);
    srt[base + s] = make_int2(rec.x & 0x1FFFF, rec.y);
  }
}

// ============ k3: FUSED gather+GEMM (unchanged from r4) ============
#define FACC(s_, p_, w_)                                                    \
  {                                                                         \
    acc1[s_][0] = fmaf(w_, __uint_as_float((p_).x << 16), acc1[s_][0]);     \
    acc1[s_][1] = fmaf(w_, __uint_as_float((p_).x & 0xffff0000u), acc1[s_][1]); \
    acc1[s_][2] = fmaf(w_, __uint_as_float((p_).y << 16), acc1[s_][2]);     \
    acc1[s_][3] = fmaf(w_, __uint_as_float((p_).y & 0xffff0000u), acc1[s_][3]); \
    acc1[s_][4] = fmaf(w_, __uint_as_float((p_).z << 16), acc1[s_][4]);     \
    acc1[s_][5] = fmaf(w_, __uint_as_float((p_).z & 0xffff0000u), acc1[s_][5]); \
    acc1[s_][6] = fmaf(w_, __uint_as_float((p_).w << 16), acc1[s_][6]);     \
    acc1[s_][7] = fmaf(w_, __uint_as_float((p_).w & 0xffff0000u), acc1[s_][7]); \
  }

__global__ __launch_bounds__(256) void fused_gather_gemm_kernel(
    const uint4* __restrict__ xh4, const short* __restrict__ xh,
    const short* __restrict__ fragW, const int* __restrict__ off,
    const int2* __restrict__ srt,
    const float* __restrict__ bl, const float* __restrict__ ba,
    float* __restrict__ out) {
  int tid = threadIdx.x;
  int wave = tid >> 6, lane = tid & 63;
  int m = lane & 15, q = lane >> 4;
  int R = blockIdx.x * 64 + wave * 16;
  int n = R + m;

  // ---- phase 1: gather z fragment into registers ----
  float acc1[4][8];
#pragma unroll
  for (int s = 0; s < 4; s++)
#pragma unroll
    for (int j = 0; j < 8; j++) acc1[s][j] = 0.f;

  int beg = 0, end = 0;
  if (n < N_NODES) {
    beg = off[n];
    end = off[n + 1];
  }
  int e = beg;
  for (; e + 1 < end; e += 2) {
    int2 r0 = srt[e];
    int2 r1 = srt[e + 1];
    uint4 p00 = xh4[(size_t)r0.x * 16 + 0 * 4 + q];
    uint4 p01 = xh4[(size_t)r0.x * 16 + 1 * 4 + q];
    uint4 p02 = xh4[(size_t)r0.x * 16 + 2 * 4 + q];
    uint4 p03 = xh4[(size_t)r0.x * 16 + 3 * 4 + q];
    uint4 p10 = xh4[(size_t)r1.x * 16 + 0 * 4 + q];
    uint4 p11 = xh4[(size_t)r1.x * 16 + 1 * 4 + q];
    uint4 p12 = xh4[(size_t)r1.x * 16 + 2 * 4 + q];
    uint4 p13 = xh4[(size_t)r1.x * 16 + 3 * 4 + q];
    float w0 = __int_as_float(r0.y), w1 = __int_as_float(r1.y);
    FACC(0, p00, w0) FACC(1, p01, w0) FACC(2, p02, w0) FACC(3, p03, w0)
    FACC(0, p10, w1) FACC(1, p11, w1) FACC(2, p12, w1) FACC(3, p13, w1)
  }
  if (e < end) {
    int2 r0 = srt[e];
    uint4 p00 = xh4[(size_t)r0.x * 16 + 0 * 4 + q];
    uint4 p01 = xh4[(size_t)r0.x * 16 + 1 * 4 + q];
    uint4 p02 = xh4[(size_t)r0.x * 16 + 2 * 4 + q];
    uint4 p03 = xh4[(size_t)r0.x * 16 + 3 * 4 + q];
    float w0 = __int_as_float(r0.y);
    FACC(0, p00, w0) FACC(1, p01, w0) FACC(2, p02, w0) FACC(3, p03, w0)
  }

  // pack to bf16 A-fragments
  bf16x8 az[4];
#pragma unroll
  for (int s = 0; s < 4; s++) {
    union { bf16x8 v; unsigned u[4]; } cv;
#pragma unroll
    for (int jj = 0; jj < 4; jj++)
      cv.u[jj] = bf16rne(acc1[s][2 * jj]) | (bf16rne(acc1[s][2 * jj + 1]) << 16);
    az[s] = cv.v;
  }

  // ---- phase 2: MFMA out = [xh | z] @ [Wl; Wa] + bl + deg*ba ----
  const short* xrow = xh + (size_t)n * D + q * 8;
  const short* fw = fragW + (size_t)lane * 8;
  f32x4 acc[8];
#pragma unroll
  for (int t = 0; t < 8; t++) acc[t] = (f32x4){0.f, 0.f, 0.f, 0.f};

#pragma unroll
  for (int s = 0; s < 8; s++) {
    bf16x8 a;
    if (s < 4)
      a = *reinterpret_cast<const bf16x8*>(xrow + s * 32);
    else
      a = az[s - 4];
#pragma unroll
    for (int t = 0; t < 8; t++) {
      bf16x8 b = *reinterpret_cast<const bf16x8*>(fw + (size_t)((s * 8 + t) * 64) * 8);
      acc[t] = __builtin_amdgcn_mfma_f32_16x16x32_bf16(a, b, acc[t], 0, 0, 0);
    }
  }

  float blv[8], bav[8];
#pragma unroll
  for (int t = 0; t < 8; t++) {
    blv[t] = bl[t * 16 + m];
    bav[t] = ba[t * 16 + m];
  }
#pragma unroll
  for (int r = 0; r < 4; r++) {
    int row = R + q * 4 + r;
    if (row < N_NODES) {
      float dg = (float)(off[row + 1] - off[row]);
#pragma unroll
      for (int t = 0; t < 8; t++)
        __builtin_nontemporal_store(acc[t][r] + blv[t] + dg * bav[t],
                                    out + (size_t)row * D + t * 16 + m);
    }
  }
}

// ================= fallback kernels (tiers 0-2) =================

__global__ __launch_bounds__(256) void hist_kernel(const int* __restrict__ ei,
                                                   int* __restrict__ cnt) {
  int e = blockIdx.x * 256 + threadIdx.x;
  if (e < N_EDGES) atomicAdd(&cnt[ei[e]], 1);
}

__global__ __launch_bounds__(256) void block_sum_kernel(const int* __restrict__ cnt,
                                                        int* __restrict__ bsum) {
  int base = blockIdx.x * SCAN_CHUNK;
  int s = 0;
#pragma unroll
  for (int k = 0; k < 4; k++) {
    int i = base + (int)threadIdx.x + k * 256;
    if (i < N_NODES) s += cnt[i];
  }
  __shared__ int red[4];
  for (int o = 32; o > 0; o >>= 1) s += __shfl_down(s, o, 64);
  if ((threadIdx.x & 63) == 0) red[threadIdx.x >> 6] = s;
  __syncthreads();
  if (threadIdx.x == 0) bsum[blockIdx.x] = red[0] + red[1] + red[2] + red[3];
}

__global__ __launch_bounds__(128) void scan_bsum_kernel(int* __restrict__ bsum,
                                                        int* __restrict__ off) {
  __shared__ int sh[128];
  int t = threadIdx.x;
  int v = (t < NB_SCAN) ? bsum[t] : 0;
  sh[t] = v;
  __syncthreads();
  for (int o = 1; o < 128; o <<= 1) {
    int add = (t >= o) ? sh[t - o] : 0;
    __syncthreads();
    sh[t] += add;
    __syncthreads();
  }
  if (t < NB_SCAN) bsum[t] = sh[t] - v;
  if (t == 0) off[N_NODES] = sh[127];
}

__global__ __launch_bounds__(256) void scan_offsets_kernel(const int* __restrict__ cnt,
                                                           const int* __restrict__ bsum,
                                                           int* __restrict__ off) {
  __shared__ int sh[256];
  int t = threadIdx.x;
  int i0 = blockIdx.x * SCAN_CHUNK + t * 4;
  int c[4];
#pragma unroll
  for (int k = 0; k < 4; k++) c[k] = (i0 + k < N_NODES) ? cnt[i0 + k] : 0;
  int ls = c[0] + c[1] + c[2] + c[3];
  sh[t] = ls;
  __syncthreads();
  for (int o = 1; o < 256; o <<= 1) {
    int add = (t >= o) ? sh[t - o] : 0;
    __syncthreads();
    sh[t] += add;
    __syncthreads();
  }
  int run = bsum[blockIdx.x] + sh[t] - ls;
#pragma unroll
  for (int k = 0; k < 4; k++) {
    if (i0 + k < N_NODES) off[i0 + k] = run;
    run += c[k];
  }
}

__global__ __launch_bounds__(256) void fill_kernel(const int* __restrict__ ei,
                                                   const float* __restrict__ ew,
                                                   const int* __restrict__ off,
                                                   int* __restrict__ cur,
                                                   int2* __restrict__ srt) {
  int e = blockIdx.x * 256 + threadIdx.x;
  if (e >= N_EDGES) return;
  int dst = ei[e];
  int p = off[dst] + atomicAdd(&cur[dst], 1);
  srt[p] = make_int2(ei[N_EDGES + e], __float_as_int(ew[e]));
}

__global__ __launch_bounds__(256) void convert_kernel(const float* __restrict__ x,
                                                      uint4* __restrict__ xh) {
  int i = blockIdx.x * 256 + threadIdx.x;
  const float4* xp = reinterpret_cast<const float4*>(x);
  float4 a = xp[(size_t)i * 2];
  float4 b = xp[(size_t)i * 2 + 1];
  uint4 o;
  o.x = bf16rne(a.x) | (bf16rne(a.y) << 16);
  o.y = bf16rne(a.z) | (bf16rne(a.w) << 16);
  o.z = bf16rne(b.x) | (bf16rne(b.y) << 16);
  o.w = bf16rne(b.z) | (bf16rne(b.w) << 16);
  xh[i] = o;
}

__global__ __launch_bounds__(256) void gather_bf16_kernel(const unsigned* __restrict__ xh,
                                                          const int* __restrict__ off,
                                                          const int2* __restrict__ srt,
                                                          float* __restrict__ z,
                                                          float* __restrict__ degf) {
  int gid = blockIdx.x * 256 + threadIdx.x;
  int n = gid >> 5;
  int lane = gid & 31;
  if (n >= N_NODES) return;
  int beg = off[n], end = off[n + 1];
  float4 acc = make_float4(0.f, 0.f, 0.f, 0.f);
  int e = beg;
  for (; e + 1 < end; e += 2) {
    int2 r0 = srt[e];
    int2 r1 = srt[e + 1];
    uint2 p0 = *reinterpret_cast<const uint2*>(xh + (size_t)r0.x * 64 + lane * 2);
    uint2 p1 = *reinterpret_cast<const uint2*>(xh + (size_t)r1.x * 64 + lane * 2);
    float w0 = __int_as_float(r0.y);
    float w1 = __int_as_float(r1.y);
    acc.x = fmaf(w0, __uint_as_float(p0.x << 16), acc.x);
    acc.y = fmaf(w0, __uint_as_float(p0.x & 0xffff0000u), acc.y);
    acc.z = fmaf(w0, __uint_as_float(p0.y << 16), acc.z);
    acc.w = fmaf(w0, __uint_as_float(p0.y & 0xffff0000u), acc.w);
    acc.x = fmaf(w1, __uint_as_float(p1.x << 16), acc.x);
    acc.y = fmaf(w1, __uint_as_float(p1.x & 0xffff0000u), acc.y);
    acc.z = fmaf(w1, __uint_as_float(p1.y << 16), acc.z);
    acc.w = fmaf(w1, __uint_as_float(p1.y & 0xffff0000u), acc.w);
  }
  if (e < end) {
    int2 r0 = srt[e];
    uint2 p0 = *reinterpret_cast<const uint2*>(xh + (size_t)r0.x * 64 + lane * 2);
    float w0 = __int_as_float(r0.y);
    acc.x = fmaf(w0, __uint_as_float(p0.x << 16), acc.x);
    acc.y = fmaf(w0, __uint_as_float(p0.x & 0xffff0000u), acc.y);
    acc.z = fmaf(w0, __uint_as_float(p0.y << 16), acc.z);
    acc.w = fmaf(w0, __uint_as_float(p0.y & 0xffff0000u), acc.w);
  }
  *reinterpret_cast<float4*>(z + (size_t)n * D + (lane << 2)) = acc;
  if (lane == 0) degf[n] = (float)(end - beg);
}

__global__ __launch_bounds__(256) void gather_f32_kernel(const float* __restrict__ x,
                                                         const int* __restrict__ off,
                                                         const int2* __restrict__ srt,
                                                         float* __restrict__ z,
                                                         float* __restrict__ degf) {
  int gid = blockIdx.x * 256 + threadIdx.x;
  int n = gid >> 5;
  int lane = gid & 31;
  if (n >= N_NODES) return;
  int beg = off[n], end = off[n + 1];
  float4 acc = make_float4(0.f, 0.f, 0.f, 0.f);
  for (int e = beg; e < end; e++) {
    int2 r0 = srt[e];
    float4 x0 = *reinterpret_cast<const float4*>(x + (size_t)r0.x * D + (lane << 2));
    float w0 = __int_as_float(r0.y);
    acc.x = fmaf(w0, x0.x, acc.x); acc.y = fmaf(w0, x0.y, acc.y);
    acc.z = fmaf(w0, x0.z, acc.z); acc.w = fmaf(w0, x0.w, acc.w);
  }
  *reinterpret_cast<float4*>(z + (size_t)n * D + (lane << 2)) = acc;
  if (lane == 0) degf[n] = (float)(end - beg);
}

__global__ __launch_bounds__(256) void scatter_kernel(const float* __restrict__ x,
                                                      const int* __restrict__ ei,
                                                      const float* __restrict__ ew,
                                                      float* __restrict__ z,
                                                      float* __restrict__ deg) {
  long long g = (long long)blockIdx.x * 256 + threadIdx.x;
  int e = (int)(g >> 5);
  int lane = (int)(g & 31);
  if (e >= N_EDGES) return;
  int dst = ei[e];
  int src = ei[N_EDGES + e];
  float w = ew[e];
  float4 xv = *reinterpret_cast<const float4*>(x + (size_t)src * D + (lane << 2));
  float* o = z + (size_t)dst * D + (lane << 2);
  atomicAdd(o + 0, w * xv.x);
  atomicAdd(o + 1, w * xv.y);
  atomicAdd(o + 2, w * xv.z);
  atomicAdd(o + 3, w * xv.w);
  if (lane == 0) atomicAdd(deg + dst, 1.0f);
}

__global__ __launch_bounds__(256) void fused_gemm_kernel(const float* __restrict__ x,
                                                         const float* __restrict__ Wl,
                                                         const float* __restrict__ bl,
                                                         const float* __restrict__ Wa,
                                                         const float* __restrict__ ba,
                                                         const float* __restrict__ deg,
                                                         float* __restrict__ out) {
  __shared__ float xs[32 * 16];
  __shared__ float zs[32 * 16];
  __shared__ float wls[16 * 128];
  __shared__ float was[16 * 128];
  const int tid = threadIdx.x;
  const int row0 = blockIdx.x * 32;
  const int c4 = tid & 31;
  const int r0 = tid >> 5;
  float4 acc[4];
#pragma unroll
  for (int i = 0; i < 4; i++) acc[i] = make_float4(0.f, 0.f, 0.f, 0.f);

  for (int k0 = 0; k0 < D; k0 += 16) {
    {
      int t = tid & 127;
      int r = t >> 2;
      int kc = (t & 3) << 2;
      const float* sp = (tid < 128) ? x : out;
      float* dp = (tid < 128) ? xs : zs;
      *reinterpret_cast<float4*>(dp + r * 16 + kc) =
          *reinterpret_cast<const float4*>(sp + (size_t)(row0 + r) * D + k0 + kc);
    }
#pragma unroll
    for (int i = 0; i < 2; i++) {
      int f = tid + i * 256;
      int kk = f >> 5;
      int cc = (f & 31) << 2;
      *reinterpret_cast<float4*>(wls + kk * 128 + cc) =
          *reinterpret_cast<const float4*>(Wl + (size_t)(k0 + kk) * D + cc);
      *reinterpret_cast<float4*>(was + kk * 128 + cc) =
          *reinterpret_cast<const float4*>(Wa + (size_t)(k0 + kk) * D + cc);
    }
    __syncthreads();
#pragma unroll
    for (int kk = 0; kk < 16; kk++) {
      float4 wl = *reinterpret_cast<const float4*>(wls + kk * 128 + (c4 << 2));
      float4 wa = *reinterpret_cast<const float4*>(was + kk * 128 + (c4 << 2));
#pragma unroll
      for (int rr = 0; rr < 4; rr++) {
        int r2 = r0 + rr * 8;
        float xv = xs[r2 * 16 + kk];
        float zv = zs[r2 * 16 + kk];
        acc[rr].x = fmaf(xv, wl.x, fmaf(zv, wa.x, acc[rr].x));
        acc[rr].y = fmaf(xv, wl.y, fmaf(zv, wa.y, acc[rr].y));
        acc[rr].z = fmaf(xv, wl.z, fmaf(zv, wa.z, acc[rr].z));
        acc[rr].w = fmaf(xv, wl.w, fmaf(zv, wa.w, acc[rr].w));
      }
    }
    __syncthreads();
  }

  float4 blv = *reinterpret_cast<const float4*>(bl + (c4 << 2));
  float4 bav = *reinterpret_cast<const float4*>(ba + (c4 << 2));
#pragma unroll
  for (int rr = 0; rr < 4; rr++) {
    int r = row0 + r0 + rr * 8;
    float d = deg[r];
    float4 o;
    o.x = acc[rr].x + blv.x + d * bav.x;
    o.y = acc[rr].y + blv.y + d * bav.y;
    o.z = acc[rr].z + blv.z + d * bav.z;
    o.w = acc[rr].w + blv.w + d * bav.w;
    *reinterpret_cast<float4*>(out + (size_t)r * D + (c4 << 2)) = o;
  }
}

extern "C" void kernel_launch(void* const* d_in, const int* in_sizes, int n_in,
                              void* d_out, int out_size, void* d_ws, size_t ws_size,
                              hipStream_t stream) {
  const float* x  = (const float*)d_in[0];
  const int*   ei = (const int*)d_in[1];
  const float* ew = (const float*)d_in[2];
  const float* Wl = (const float*)d_in[3];
  const float* bl = (const float*)d_in[4];
  const float* Wa = (const float*)d_in[5];
  const float* ba = (const float*)d_in[6];
  float* out = (float*)d_out;

  if (ws_size >= WS_T5_BYTES) {
    int* ws = (int*)d_ws;
    int* off = ws + T5_OFF;
    unsigned short* fragW = (unsigned short*)(ws + T5_FRAGW);
    int2* srt = (int2*)(ws + T5_SRT);
    unsigned* xh = (unsigned*)(ws + T5_XH);
    int2* stage = (int2*)(ws + T5_ZH);
    int* pcur = ws + T7_PCUR;

    hipMemsetAsync(pcur, 0, NBUCK * PCUR_STRIDE * sizeof(int), stream);
    part_kernel<<<PART_BLOCKS + CONV_BLOCKS + W_BLOCKS, 256, 0, stream>>>(
        ei, ew, x, Wl, Wa, pcur, stage, (uint4*)xh, fragW);
    binB2_kernel<<<NBUCK, 1024, 0, stream>>>(pcur, stage, off, srt);
    fused_gather_gemm_kernel<<<1563, 256, 0, stream>>>(
        (const uint4*)xh, (const short*)xh, (const short*)fragW, off, srt,
        bl, ba, out);
  } else if (ws_size >= WS_T1_BYTES) {
    int*  cnt  = (int*)d_ws;
    int*  off  = cnt + WS_OFF;
    int*  bsum = cnt + WS_BSUM;
    int2* srt  = (int2*)(cnt + WS_SRT);
    float* degf = (float*)cnt;

    hipMemsetAsync(cnt, 0, (size_t)N_NODES * sizeof(int), stream);
    hist_kernel<<<(N_EDGES + 255) / 256, 256, 0, stream>>>(ei, cnt);
    block_sum_kernel<<<NB_SCAN, 256, 0, stream>>>(cnt, bsum);
    scan_bsum_kernel<<<1, 128, 0, stream>>>(bsum, off);
    scan_offsets_kernel<<<NB_SCAN, 256, 0, stream>>>(cnt, bsum, off);
    hipMemsetAsync(cnt, 0, (size_t)N_NODES * sizeof(int), stream);
    fill_kernel<<<(N_EDGES + 255) / 256, 256, 0, stream>>>(ei, ew, off, cnt, srt);

    if (ws_size >= WS_T2_BYTES) {
      unsigned* xh = (unsigned*)(cnt + WS_XH);
      convert_kernel<<<(N_NODES * D / 8) / 256, 256, 0, stream>>>(x, (uint4*)xh);
      gather_bf16_kernel<<<(N_NODES * 32 + 255) / 256, 256, 0, stream>>>(xh, off, srt, out, degf);
    } else {
      gather_f32_kernel<<<(N_NODES * 32 + 255) / 256, 256, 0, stream>>>(x, off, srt, out, degf);
    }
    fused_gemm_kernel<<<N_NODES / 32, 256, 0, stream>>>(x, Wl, bl, Wa, ba, degf, out);
  } else {
    float* deg = (float*)d_ws;
    hipMemsetAsync(out, 0, (size_t)N_NODES * D * sizeof(float), stream);
    hipMemsetAsync(deg, 0, (size_t)N_NODES * sizeof(float), stream);
    scatter_kernel<<<(N_EDGES * 32) / 256, 256, 0, stream>>>(x, ei, ew, out, deg);
    fused_gemm_kernel<<<N_NODES / 32, 256, 0, stream>>>(x, Wl, bl, Wa, ba, deg, out);
  }
}